// Round 11
// baseline (569.730 us; speedup 1.0000x reference)
//
#include <hip/hip_runtime.h>

// numpy never contracts mul+add: products are rounded then added. File-wide.
// The sgemm dot uses __builtin_fmaf explicitly (OpenBLAS vfmadd231ps).
#pragma clang fp contract(off)

#define NN 512
#define DD 256

typedef int int4v __attribute__((ext_vector_type(4)));

// ---------------------------------------------------------------------------
// numpy f32 pairwise-sum leaf, n=128, AVX512 path (npyv width 16):
//   8 vector accumulators = straight loads of x[0..127] (8*16 == 128, zero
//   loop iterations), vector tree ((v0+v1)+(v2+v3))+((v4+v5)+(v6+v7)) giving
//   lane partials p_i = tree over x[16j+i]^2, then _mm512_reduce_add_ps
//   lane-halving: (i,i+8),(i,i+4),(i,i+2),(i,i+1).
// Products fl(x*x) rounded individually (emb*emb materialized by numpy).
// ---------------------------------------------------------------------------
__device__ __forceinline__ float np_leaf128_avx512(const float* __restrict__ x)
{
    float p[16];
    #pragma unroll
    for (int i = 0; i < 16; ++i) {
        const float q0 = x[i]       * x[i];
        const float q1 = x[i + 16]  * x[i + 16];
        const float q2 = x[i + 32]  * x[i + 32];
        const float q3 = x[i + 48]  * x[i + 48];
        const float q4 = x[i + 64]  * x[i + 64];
        const float q5 = x[i + 80]  * x[i + 80];
        const float q6 = x[i + 96]  * x[i + 96];
        const float q7 = x[i + 112] * x[i + 112];
        p[i] = ((q0 + q1) + (q2 + q3)) + ((q4 + q5) + (q6 + q7));
    }
    float q[8];
    #pragma unroll
    for (int i = 0; i < 8; ++i) q[i] = p[i] + p[i + 8];
    const float s0 = q[0] + q[4];
    const float s1 = q[1] + q[5];
    const float s2 = q[2] + q[6];
    const float s3 = q[3] + q[7];
    const float u0 = s0 + s2;
    const float u1 = s1 + s3;
    return u0 + u1;
}

// ---------------------------------------------------------------------------
// Fused TripletMarginMiner replicating the numpy-f32 golden:
//   sq   : np.sum(emb*emb, axis=1): pairwise n=256 -> leaf(0..127) +
//          leaf(128..255), AVX512 SIMD leaves (above).
//   dot  : OpenBLAS sgemm: single f32 accumulator, sequential k, FMA.
//   mat  : fl32( fl32(sq_a+sq_j) - fl32(2*dot) ), relu.
//   mask : sames(a,p)&(p!=a)&diffs(a,n)&(fl32(mat_an-mat_ap) <= 0.2f)
//          validity folded: dn=+inf (diff fails), mp=NaN (same fails).
// Structure (layout/validity/labels/int32-out) verified correct by the R10
// far/boundary probe (absmax 1.0, no far flips).
// One block per anchor a; 512 threads; coalesced int4 stores, n fastest.
// ---------------------------------------------------------------------------
__global__ __launch_bounds__(512)
void triplet_kernel(const float* __restrict__ emb,
                    const int* __restrict__ lab,
                    int* __restrict__ out)
{
    __shared__ int   canon[NN];
    __shared__ float arow[DD];
    __shared__ float dn[NN];
    __shared__ float mp[NN];
    __shared__ float sq_a_sh;
    __shared__ int   det_lab64;

    const int a = blockIdx.x;
    const int t = threadIdx.x;   // 0..511

    // labels width canonicalization (values in [0,32): int64 staging has all
    // 256 odd int32 words zero; genuine int32 fails that w.p. 1-32^-256)
    if (t == 0) det_lab64 = 0;
    __syncthreads();
    if (t < 256 && lab[2 * t + 1] == 0) atomicAdd(&det_lab64, 1);
    __syncthreads();
    canon[t] = (det_lab64 == 256) ? lab[2 * t] : lab[t];

    if (t < DD) arow[t] = emb[(size_t)a * DD + t];
    __syncthreads();

    // ---- sq_j: numpy SIMD pairwise ----
    const float* __restrict__ xr = emb + (size_t)t * DD;
    const float sqj = np_leaf128_avx512(xr) + np_leaf128_avx512(xr + 128);
    if (t == a) sq_a_sh = sqj;

    // ---- dot(a,j): sequential-k single-accumulator FMA (sgemm kernel) ----
    float dot = 0.0f;
    for (int k = 0; k < DD; ++k)
        dot = __builtin_fmaf(arow[k], xr[k], dot);
    __syncthreads();   // sq_a_sh visible

    // ---- mat[a][t], f32, numpy op tree ----
    const float t1 = sq_a_sh + sqj;
    const float t2 = 2.0f * dot;       // exact scale
    float m = t1 - t2;
    m = m > 0.0f ? m : 0.0f;

    const int la = canon[a];
    dn[t] = (canon[t] != la) ? m : __builtin_inff();
    mp[t] = (canon[t] == la && t != a) ? m : __builtin_nanf("");
    __syncthreads();

    // ---- write the 512x512 int32 slab, n fastest, coalesced int4 ----
    const int tx = t & 127;      // 4 consecutive n per thread
    const int ty = t >> 7;       // 0..3 strides p
    const float d0 = dn[4 * tx + 0];
    const float d1 = dn[4 * tx + 1];
    const float d2 = dn[4 * tx + 2];
    const float d3 = dn[4 * tx + 3];

    int4v* base = (int4v*)out + (size_t)a * NN * (NN / 4) + tx;
    for (int p = ty; p < NN; p += 4) {
        const float mpp = mp[p];             // LDS broadcast
        int4v r;
        r.x = ((d0 - mpp) <= 0.2f) ? 1 : 0;  // inf/NaN fold validity to 0
        r.y = ((d1 - mpp) <= 0.2f) ? 1 : 0;
        r.z = ((d2 - mpp) <= 0.2f) ? 1 : 0;
        r.w = ((d3 - mpp) <= 0.2f) ? 1 : 0;
        base[(size_t)p * (NN / 4)] = r;
    }
}

// ---------------------------------------------------------------------------
extern "C" void kernel_launch(void* const* d_in, const int* in_sizes, int n_in,
                              void* d_out, int out_size, void* d_ws, size_t ws_size,
                              hipStream_t stream)
{
    const float* emb    = (const float*)d_in[0];
    const int*   labels = (const int*)d_in[1];
    int*         out    = (int*)d_out;
    (void)d_ws; (void)ws_size;

    triplet_kernel<<<NN, 512, 0, stream>>>(emb, labels, out);
}